// Round 4
// baseline (54.016 us; speedup 1.0000x reference)
//
#include <hip/hip_runtime.h>

// DifferentiableCIndexLoss:
//   mask[i,j] = (t[i] < t[j]) && (e[i]==1)
//   loss = sum sigmoid((r[j]-r[i])/SIGMA) * mask ;  count = sum mask
//   out  = loss / (count + 1e-6)
//
// R3: bucket-sort both the active rows (e==1) and all columns by time
// (2048 buckets), then classify (row-chunk x j-page) tiles via bucket-id
// bounds: all-false -> skip; all-true -> no compare, analytic count, inner
// loop = fma+rcp+add; mixed (diagonal band, ~4%) -> exact per-pair compare.
// Sorting is EXACT for the mask: all-true/false proofs use strict bucket
// inequalities; equal-bucket tiles fall to exact compares.
// Prep (hist -> scan+bounds -> scatter) is ONE kernel with a last-block
// spin barrier (64 blocks, co-resident by construction).

#define BLOCK 256
#define NB 2048            // time buckets
#define ROWCHUNK 512       // rows per tile (2 per thread)
#define RC_SHIFT 9
#define JPAGE 64           // j columns per tile
#define JP_SHIFT 6
#define GRID_MAIN 2048

__device__ __forceinline__ float fast_exp2(float x) { return __builtin_amdgcn_exp2f(x); }
__device__ __forceinline__ float fast_rcp(float x)  { return __builtin_amdgcn_rcpf(x); }
__device__ __forceinline__ float clamp60(float x)   { return fminf(fmaxf(x, -60.0f), 60.0f); }

__device__ __forceinline__ int bucket_of(float tv) {
    int b = (int)(tv * (float)NB);
    return min(max(b, 0), NB - 1);
}

// ---------------- prep: hist -> (last block) scan + bounds -> scatter --------
__global__ __launch_bounds__(BLOCK) void cindex_prep(
    const float* __restrict__ r, const float* __restrict__ t,
    const int* __restrict__ ev, int B, float kscale, int nblocks,
    int* __restrict__ ctrl,            // [0]=arrive, [1]=release, [3]=nactive
    int* __restrict__ histI, int* __restrict__ histJ,
    int* __restrict__ curI,  int* __restrict__ curJ,
    int* __restrict__ rcLoB, int* __restrict__ rcHiB,
    int* __restrict__ jpLoB, int* __restrict__ jpHiB,
    float2* __restrict__ sortedI, float2* __restrict__ sortedJ) {

    const int tid = threadIdx.x;
    const int gid = blockIdx.x * BLOCK + tid;
    float tv = 0.f, rv = 0.f; int e = 0, b = 0;
    const bool has = (gid < B);
    if (has) {
        tv = t[gid]; rv = r[gid]; e = ev[gid];
        b = bucket_of(tv);
        atomicAdd(&histJ[b], 1);
        if (e == 1) atomicAdd(&histI[b], 1);
    }
    __syncthreads();
    __threadfence();
    __shared__ int amLast;
    if (tid == 0) {
        int old = atomicAdd(&ctrl[0], 1);
        amLast = (old == nblocks - 1);
    }
    __syncthreads();

    if (amLast) {
        // ---- scan both histograms + derive chunk/page bucket bounds ----
        const int nrc = B / ROWCHUNK;      // 32
        const int npg = B / JPAGE;         // 256
        __shared__ int ts[BLOCK];
        __shared__ int rcLo_s[64], rcHi_s[64];
        __shared__ int jpLo_s[512], jpHi_s[512];
        for (int i = tid; i < nrc; i += BLOCK) { rcLo_s[i] = 0x7fffffff; rcHi_s[i] = -1; }
        for (int i = tid; i < npg; i += BLOCK) { jpLo_s[i] = 0x7fffffff; jpHi_s[i] = -1; }
        __syncthreads();

        const int b0 = tid * (NB / BLOCK);   // 8 buckets per thread
        // ---- histI ----
        {
            int cnt[NB / BLOCK], pre[NB / BLOCK]; int s = 0;
#pragma unroll
            for (int k = 0; k < NB / BLOCK; ++k) {
                int v = __hip_atomic_load(&histI[b0 + k], __ATOMIC_RELAXED, __HIP_MEMORY_SCOPE_AGENT);
                cnt[k] = v; pre[k] = s; s += v;
            }
            ts[tid] = s; __syncthreads();
            for (int off = 1; off < BLOCK; off <<= 1) {
                int v = (tid >= off) ? ts[tid - off] : 0;
                __syncthreads();
                ts[tid] += v;
                __syncthreads();
            }
            int excl = ts[tid] - s;
            if (tid == BLOCK - 1) ctrl[3] = ts[BLOCK - 1];   // nactive
#pragma unroll
            for (int k = 0; k < NB / BLOCK; ++k) {
                int o = excl + pre[k];
                __hip_atomic_store(&curI[b0 + k], o, __ATOMIC_RELAXED, __HIP_MEMORY_SCOPE_AGENT);
                if (cnt[k] > 0) {
                    int c0 = o >> RC_SHIFT, c1 = (o + cnt[k] - 1) >> RC_SHIFT;
                    for (int c = c0; c <= c1; ++c) {
                        atomicMin(&rcLo_s[c], b0 + k);
                        atomicMax(&rcHi_s[c], b0 + k);
                    }
                }
            }
            __syncthreads();
        }
        // ---- histJ ----
        {
            int cnt[NB / BLOCK], pre[NB / BLOCK]; int s = 0;
#pragma unroll
            for (int k = 0; k < NB / BLOCK; ++k) {
                int v = __hip_atomic_load(&histJ[b0 + k], __ATOMIC_RELAXED, __HIP_MEMORY_SCOPE_AGENT);
                cnt[k] = v; pre[k] = s; s += v;
            }
            ts[tid] = s; __syncthreads();
            for (int off = 1; off < BLOCK; off <<= 1) {
                int v = (tid >= off) ? ts[tid - off] : 0;
                __syncthreads();
                ts[tid] += v;
                __syncthreads();
            }
            int excl = ts[tid] - s;
#pragma unroll
            for (int k = 0; k < NB / BLOCK; ++k) {
                int o = excl + pre[k];
                __hip_atomic_store(&curJ[b0 + k], o, __ATOMIC_RELAXED, __HIP_MEMORY_SCOPE_AGENT);
                if (cnt[k] > 0) {
                    int c0 = o >> JP_SHIFT, c1 = (o + cnt[k] - 1) >> JP_SHIFT;
                    for (int c = c0; c <= c1; ++c) {
                        atomicMin(&jpLo_s[c], b0 + k);
                        atomicMax(&jpHi_s[c], b0 + k);
                    }
                }
            }
            __syncthreads();
        }
        for (int i = tid; i < nrc; i += BLOCK) { rcLoB[i] = rcLo_s[i]; rcHiB[i] = rcHi_s[i]; }
        for (int i = tid; i < npg; i += BLOCK) { jpLoB[i] = jpLo_s[i]; jpHiB[i] = jpHi_s[i]; }
        __syncthreads();
        __threadfence();
        if (tid == 0)
            __hip_atomic_store(&ctrl[1], 1, __ATOMIC_RELEASE, __HIP_MEMORY_SCOPE_AGENT);
    } else {
        if (tid == 0) {
            while (__hip_atomic_load(&ctrl[1], __ATOMIC_ACQUIRE, __HIP_MEMORY_SCOPE_AGENT) == 0)
                __builtin_amdgcn_s_sleep(16);
        }
        __syncthreads();
    }

    // ---- scatter ----
    if (has) {
        float s = clamp60(rv * kscale);
        float F = fast_exp2(-s);
        int pos = atomicAdd(&curJ[b], 1);
        sortedJ[pos] = make_float2(F, tv);
        if (e == 1) {
            float E = fast_exp2(s);
            int posI = atomicAdd(&curI[b], 1);
            sortedI[posI] = make_float2(E, tv);
        }
    }
}

// ---------------- main: classified tiles over sorted arrays -----------------
__global__ __launch_bounds__(BLOCK) void cindex_main(
    const float2* __restrict__ sortedI, const float2* __restrict__ sortedJ,
    const int* __restrict__ rcLoB, const int* __restrict__ rcHiB,
    const int* __restrict__ jpLoB, const int* __restrict__ jpHiB,
    const int* __restrict__ ctrl,
    float* __restrict__ pL, unsigned int* __restrict__ pC,
    int B, int ntiles, int npg) {

    const int tid = threadIdx.x;
    const int nactive = ctrl[3];
    __shared__ float2 tile[JPAGE];

    float lsum = 0.0f;
    int   csum = 0;

    for (int tidx = blockIdx.x; tidx < ntiles; tidx += gridDim.x) {
        int rc = tidx / npg;
        int p  = tidx - rc * npg;
        int rl = rcLoB[rc], rh = rcHiB[rc];
        int jl = jpLoB[p],  jh = jpHiB[p];
        if (rl > jh) continue;               // all-false (incl. empty chunks)
        bool alltrue = (rh < jl);

        // my 2 rows (contiguous, coalesced)
        float Ei0, Ei1, ti0, ti1; int v0, v1;
        {
            int rr0 = rc * ROWCHUNK + tid;
            int rr1 = rr0 + BLOCK;
            v0 = rr0 < nactive; v1 = rr1 < nactive;
            if (v0) { float2 f = sortedI[rr0]; Ei0 = f.x; ti0 = f.y; }
            else    { Ei0 = __builtin_inff(); ti0 = 3.0f; }
            if (v1) { float2 f = sortedI[rr1]; Ei1 = f.x; ti1 = f.y; }
            else    { Ei1 = __builtin_inff(); ti1 = 3.0f; }
        }
        __syncthreads();
        if (tid < JPAGE) tile[tid] = sortedJ[p * JPAGE + tid];
        __syncthreads();

        if (alltrue) {
            float l0 = 0.f, l1 = 0.f;
#pragma unroll 8
            for (int jj = 0; jj < JPAGE; ++jj) {
                float Fj = tile[jj].x;
                l0 += fast_rcp(__builtin_fmaf(Ei0, Fj, 1.0f));   // inf rows -> 0
                l1 += fast_rcp(__builtin_fmaf(Ei1, Fj, 1.0f));
            }
            lsum += l0 + l1;
            csum += (v0 + v1) * JPAGE;
        } else {
            float l0 = 0.f, l1 = 0.f; int c0 = 0, c1 = 0;
#pragma unroll 4
            for (int jj = 0; jj < JPAGE; ++jj) {
                float2 q = tile[jj];
                float s0 = fast_rcp(__builtin_fmaf(Ei0, q.x, 1.0f));
                float s1 = fast_rcp(__builtin_fmaf(Ei1, q.x, 1.0f));
                bool m0 = ti0 < q.y, m1 = ti1 < q.y;
                l0 += m0 ? s0 : 0.0f; c0 += m0;
                l1 += m1 ? s1 : 0.0f; c1 += m1;
            }
            lsum += l0 + l1;
            csum += c0 + c1;
        }
    }

    // block reduce
#pragma unroll
    for (int off = 32; off > 0; off >>= 1) {
        lsum += __shfl_down(lsum, off);
        csum += __shfl_down(csum, off);
    }
    __shared__ float lw[BLOCK / 64];
    __shared__ int   cw[BLOCK / 64];
    int wid = tid >> 6;
    if ((tid & 63) == 0) { lw[wid] = lsum; cw[wid] = csum; }
    __syncthreads();
    if (tid == 0) {
        pL[blockIdx.x] = (lw[0] + lw[1]) + (lw[2] + lw[3]);
        pC[blockIdx.x] = (unsigned)((cw[0] + cw[1]) + (cw[2] + cw[3]));
    }
}

__global__ __launch_bounds__(BLOCK) void cindex_finalize(
    const float* __restrict__ pL, const unsigned int* __restrict__ pC,
    int n, float* __restrict__ out) {
    double l = 0.0, c = 0.0;
    for (int i = threadIdx.x; i < n; i += BLOCK) {
        l += (double)pL[i];
        c += (double)pC[i];
    }
#pragma unroll
    for (int off = 32; off > 0; off >>= 1) {
        l += __shfl_down(l, off);
        c += __shfl_down(c, off);
    }
    __shared__ double lw[BLOCK / 64], cw[BLOCK / 64];
    int wid = threadIdx.x >> 6;
    if ((threadIdx.x & 63) == 0) { lw[wid] = l; cw[wid] = c; }
    __syncthreads();
    if (threadIdx.x == 0) {
        double L = (lw[0] + lw[1]) + (lw[2] + lw[3]);
        double C = (cw[0] + cw[1]) + (cw[2] + cw[3]);
        out[0] = (float)(L / (C + 1e-6));
    }
}

extern "C" void kernel_launch(void* const* d_in, const int* in_sizes, int n_in,
                              void* d_out, int out_size, void* d_ws, size_t ws_size,
                              hipStream_t stream) {
    const float* r  = (const float*)d_in[0];
    const float* t  = (const float*)d_in[1];
    const int*   ev = (const int*)d_in[2];
    float* out = (float*)d_out;
    const int B = in_sizes[0];   // 16384

    const float SIGMA = 0.1f;
    const float LOG2E = 1.4426950408889634f;
    const float kscale = LOG2E / SIGMA;

    const int nrc = B / ROWCHUNK;           // 32
    const int npg = B / JPAGE;              // 256
    const int ntiles = nrc * npg;           // 8192

    char* ws = (char*)d_ws;
    int*    ctrl    = (int*)(ws + 0);        // 16 B used, 64 reserved
    int*    histI   = (int*)(ws + 64);
    int*    histJ   = (int*)(ws + 64 + 4 * NB);
    int*    curI    = (int*)(ws + 64 + 8 * NB);
    int*    curJ    = (int*)(ws + 64 + 12 * NB);
    int*    rcLoB   = (int*)(ws + 64 + 16 * NB);
    int*    rcHiB   = rcLoB + nrc;
    int*    jpLoB   = rcHiB + nrc;
    int*    jpHiB   = jpLoB + npg;
    float2* sortedI = (float2*)(ws + 40960);
    float2* sortedJ = (float2*)(ws + 40960 + (size_t)B * 8);
    float*  pL      = (float*)(ws + 40960 + (size_t)B * 16);
    unsigned int* pC = (unsigned int*)((char*)pL + (size_t)GRID_MAIN * 4);

    const int nblkPrep = (B + BLOCK - 1) / BLOCK;   // 64

    // zero: ctrl + both histograms (everything the prep accumulates into)
    hipMemsetAsync(ws, 0, 64 + 8 * NB, stream);
    cindex_prep<<<nblkPrep, BLOCK, 0, stream>>>(r, t, ev, B, kscale, nblkPrep,
        ctrl, histI, histJ, curI, curJ, rcLoB, rcHiB, jpLoB, jpHiB, sortedI, sortedJ);
    cindex_main<<<GRID_MAIN, BLOCK, 0, stream>>>(sortedI, sortedJ,
        rcLoB, rcHiB, jpLoB, jpHiB, ctrl, pL, pC, B, ntiles, npg);
    cindex_finalize<<<1, BLOCK, 0, stream>>>(pL, pC, GRID_MAIN, out);
}